// Round 9
// baseline (275.192 us; speedup 1.0000x reference)
//
#include <hip/hip_runtime.h>
#include <hip/hip_bf16.h>

// y_i = x_i^T Q x_i + b^T x_i + c ; N=16384, D=1024, fp32.
// Round 13 == Round 12 resubmitted verbatim (bench infra failed twice;
// no counters, no verdict). Audit re-confirmed: qb bounds exactly 2MB,
// wave-uniform barriers, dump/read race-free, static reg indices.
// ---
// Round 12: R11's structure (wave-private k-eighths, B direct L2->reg,
// phase-only barriers) minus the register overrun that spilled it.
// R11 post-mortem: WRITE 88MB / VGPR 128+64AGPR = exactly the (512,2)
// 192-arch budget -> spilled; overrun = 16 scalar b32 dot reads + temps.
// Fixes:
//  - xvT TRANSPOSED [phase][col][row], stride 68 f32: dot = 4 x
//    ds_read_b128 (r consecutive) instead of 16 x b32. Per-quarter-wave
//    start banks 2-way -> free. LDS total 37KB.
//  - phases of 64 cols (16 barriers); dumps use static a-indices via
//    pn&1 branch (rule 20).
//  - __launch_bounds__(512,1): grid 256 = 1 block/CU by construction,
//    so the (512,2) reg cap bought nothing but the spill cliff. 512-thr
//    block => 2 waves/SIMD minimum => 256 unified budget; spill gone.
// Floor: L2 32KB/CU/round ~585cyc x 64 rounds ~16us + ~10us x-prologue.
// Tripwire: WRITE_SIZE >> 2.2MB = spill -> fall back to R10+xvT.
// 8 waves own DISJOINT k-eighths (128k) of all 64 rows; a[4][4] = 64
// AGPR; full-K blocks -> direct y stores, no atomics/memset.

#define DD 1024
#define XTR 68                 // xvT col stride in floats (64 rows + 4 pad)

typedef short v8s __attribute__((ext_vector_type(8)));
typedef float v4f __attribute__((ext_vector_type(4)));

__device__ __forceinline__ short f2b(float f) {
    union { __hip_bfloat16 h; short s; } u;
    u.h = __float2bfloat16(f);
    return u.s;
}
__device__ __forceinline__ float b2f(short s) {
    union { unsigned u; float f; } uu;
    uu.u = ((unsigned)(unsigned short)s) << 16;
    return uu.f;
}

#define MFMA16(A, B, C) __builtin_amdgcn_mfma_f32_16x16x32_bf16(A, B, C, 0, 0, 0)

// pass 1: Q fp32 -> bf16, frag-ordered segments in d_ws (2 MB).
// Q[n][k] -> seg (t=n>>4, e=k>>7), byte s*1024 + (quad*16 + n&15)*16 + j*2,
// s=(k&127)>>5, quad=(k&31)>>3, j=k&7.  (B := Q^T via x^TQx == x^TQ^Tx.)
__global__ __launch_bounds__(256, 4)
void cvt_kernel(const float* __restrict__ Q, char* __restrict__ qb)
{
    const int gid = blockIdx.x * 256 + threadIdx.x;   // 131072 threads
    const int n  = gid >> 7;          // Q row 0..1023
    const int k8 = gid & 127;         // 8-elem group within row
    const float4 f0 = *(const float4*)(Q + (size_t)n * DD + k8 * 8);
    const float4 f1 = *(const float4*)(Q + (size_t)n * DD + k8 * 8 + 4);
    v8s t;
    t[0]=f2b(f0.x); t[1]=f2b(f0.y); t[2]=f2b(f0.z); t[3]=f2b(f0.w);
    t[4]=f2b(f1.x); t[5]=f2b(f1.y); t[6]=f2b(f1.z); t[7]=f2b(f1.w);
    const int tt = n >> 4, l15 = n & 15;
    const int e = k8 >> 4, rem = k8 & 15, s = rem >> 2, quad = rem & 3;
    char* dst = qb + ((size_t)(tt * 8 + e) << 12) + s * 1024 + (quad * 16 + l15) * 16;
    *(v8s*)dst = t;
}

// load this wave's 4 B-frags for one tile from pointer P (coalesced 1KB/instr)
#define LOADB(B0, B1, B2, B3, P)                                          \
  { B0 = *(const v8s*)(P);                                                \
    B1 = *(const v8s*)((P) + 1024);                                       \
    B2 = *(const v8s*)((P) + 2048);                                       \
    B3 = *(const v8s*)((P) + 3072); }

// dump one A-frag FR (kstep with phase-local col base CB) transposed:
// xvT[col][row] = x value. col = CB + quad*8 + j, row = g*16 + l15.
#define DUMP1(BASE, FR, CB, G)                                            \
  { _Pragma("unroll")                                                     \
    for (int j = 0; j < 8; ++j)                                           \
      (BASE)[((CB) + quad * 8 + j) * XTR + (G) * 16 + l15] = b2f((FR)[j]); }

// one 16-col round: 16 MFMA (4 independent g-chains) + transposed dot.
// P = phase (runtime), U = round-in-phase (compile-time 0..3).
#define ROUND(B0, B1, B2, B3, P, U)                                       \
  { const float* xq_ = &xvT[(P) & 1][((U) * 16 + l15) * XTR + quad * 4];  \
    const float bb_ = (e == 0) ? bvec[((P) * 4 + (U)) * 16 + l15] : 0.f;  \
    _Pragma("unroll")                                                     \
    for (int g = 0; g < 4; ++g) {                                         \
      v4f c_ = (v4f){0.f, 0.f, 0.f, 0.f};                                 \
      c_ = MFMA16(a[g][0], B0, c_);                                       \
      c_ = MFMA16(a[g][1], B1, c_);                                       \
      c_ = MFMA16(a[g][2], B2, c_);                                       \
      c_ = MFMA16(a[g][3], B3, c_);                                       \
      const v4f xv_ = *(const v4f*)(xq_ + g * 16);                        \
      _Pragma("unroll")                                                   \
      for (int r = 0; r < 4; ++r)                                         \
        acc[g][r] += (c_[r] + bb_) * xv_[r];                              \
    } }

__global__ __launch_bounds__(512, 1)
void quad_kernel(const float* __restrict__ x, const char* __restrict__ qb,
                 const float* __restrict__ bvec, const float* __restrict__ cptr,
                 float* __restrict__ y)
{
    __shared__ __align__(16) float xvT[2][64 * XTR];  // 34.8 KB, phase dbuf
    __shared__ float yred[8][64];                     //  2.0 KB

    const int tid  = threadIdx.x;
    const int lane = tid & 63;
    const int e    = tid >> 6;       // 0..7: owns k-eighth [e*128, +128)
    const int quad = lane >> 4;
    const int l15  = lane & 15;

    const int row_base = blockIdx.x * 64;

    // ---- B tile-0 loads first (in flight under the whole A prologue) ----
    const char* qp = qb + ((size_t)e << 12) + lane * 16;
    v8s bA0, bA1, bA2, bA3, bB0, bB1, bB2, bB3;
    LOADB(bA0, bA1, bA2, bA3, qp);
    qp += 32768;                     // -> tile 1

    // ---- A prologue: x[64 rows][e's 128 k] -> a[4][4] bf16 in AGPRs ----
    // A-frag (16x16x32): m = l15, k = quad*8 + j.
    v8s a[4][4];
    #pragma unroll
    for (int g = 0; g < 4; ++g) {
        const float* xr = x + (size_t)(row_base + g * 16 + l15) * DD
                        + e * 128 + quad * 8;
        #pragma unroll
        for (int s = 0; s < 4; ++s) {
            const float4 f0 = *(const float4*)(xr + s * 32);
            const float4 f1 = *(const float4*)(xr + s * 32 + 4);
            v8s t;
            t[0]=f2b(f0.x); t[1]=f2b(f0.y); t[2]=f2b(f0.z); t[3]=f2b(f0.w);
            t[4]=f2b(f1.x); t[5]=f2b(f1.y); t[6]=f2b(f1.z); t[7]=f2b(f1.w);
            a[g][s] = t;
            asm volatile("" : "+a"(a[g][s]));   // steer to AGPR
        }
    }

    // phase-0 xv dump (cols 0..63 = e0's ksteps 0,1), static indices
    if (e == 0) {
        float* base = &xvT[0][0];
        #pragma unroll
        for (int g = 0; g < 4; ++g) {
            DUMP1(base, a[g][0],  0, g);
            DUMP1(base, a[g][1], 32, g);
        }
    }
    __syncthreads();

    float acc[4][4];
    #pragma unroll
    for (int g = 0; g < 4; ++g)
        #pragma unroll
        for (int r = 0; r < 4; ++r) acc[g][r] = 0.f;

    for (int p = 0; p < 16; ++p) {
        if (p) __syncthreads();      // phase boundary (15 + prologue's 1)

        // dump next phase's xv into the other buffer. Its old content
        // (phase p-1) was last read before the barrier above; readers of
        // phase p+1 start only after the next barrier.
        const int pn = p + 1;
        if (pn < 16 && e == (pn >> 1)) {
            float* base = &xvT[pn & 1][0];
            if (pn & 1) {
                #pragma unroll
                for (int g = 0; g < 4; ++g) {
                    DUMP1(base, a[g][2],  0, g);
                    DUMP1(base, a[g][3], 32, g);
                }
            } else {
                #pragma unroll
                for (int g = 0; g < 4; ++g) {
                    DUMP1(base, a[g][0],  0, g);
                    DUMP1(base, a[g][1], 32, g);
                }
            }
        }

        // 4 rounds, B reg-dbuf: load t+1 before computing t; waves
        // free-run inside the phase (no barriers), L2 latency hides
        // under the other wave on the SIMD + the prefetch distance.
        LOADB(bB0, bB1, bB2, bB3, qp); qp += 32768;
        ROUND(bA0, bA1, bA2, bA3, p, 0);
        LOADB(bA0, bA1, bA2, bA3, qp); qp += 32768;
        ROUND(bB0, bB1, bB2, bB3, p, 1);
        LOADB(bB0, bB1, bB2, bB3, qp); qp += 32768;
        ROUND(bA0, bA1, bA2, bA3, p, 2);
        if (p < 15) { LOADB(bA0, bA1, bA2, bA3, qp); qp += 32768; }
        ROUND(bB0, bB1, bB2, bB3, p, 3);
    }

    // ---- reduce 16 l15-lanes (shfl), then 8 k-eighth waves (LDS) ----
    #pragma unroll
    for (int g = 0; g < 4; ++g)
        #pragma unroll
        for (int r = 0; r < 4; ++r) {
            float v = acc[g][r];
            v += __shfl_xor(v, 1); v += __shfl_xor(v, 2);
            v += __shfl_xor(v, 4); v += __shfl_xor(v, 8);
            if (l15 == 0)
                yred[e][g * 16 + quad * 4 + r] = v;
        }
    __syncthreads();
    if (tid < 64) {
        float s = yred[0][tid] + yred[1][tid] + yred[2][tid] + yred[3][tid]
                + yred[4][tid] + yred[5][tid] + yred[6][tid] + yred[7][tid];
        y[row_base + tid] = s + cptr[0];
    }
}

extern "C" void kernel_launch(void* const* d_in, const int* in_sizes, int n_in,
                              void* d_out, int out_size, void* d_ws, size_t ws_size,
                              hipStream_t stream)
{
    const float* x = (const float*)d_in[0];
    const float* Q = (const float*)d_in[1];
    const float* b = (const float*)d_in[2];
    const float* c = (const float*)d_in[3];
    float* y = (float*)d_out;
    char* qb = (char*)d_ws;   // 2 MB bf16 frag-ordered Q image

    cvt_kernel<<<dim3(512), dim3(256), 0, stream>>>(Q, qb);
    quad_kernel<<<dim3(256), dim3(512), 0, stream>>>(x, qb, b, c, y);
}